// Round 7
// baseline (378.699 us; speedup 1.0000x reference)
//
#include <hip/hip_runtime.h>
#include <hip/hip_bf16.h>

// Problem constants: B=4, S=2048, D=1024, H=16, dk=64
#define SEQ   2048
#define NB    4
#define NH    16
#define DK    64
#define DM    1024
#define MROWS (NB * SEQ)   // 8192

typedef __bf16 bf16_t;
typedef __bf16 bf16x8 __attribute__((ext_vector_type(8)));
typedef __bf16 bf16x4 __attribute__((ext_vector_type(4)));
typedef float  f32x4  __attribute__((ext_vector_type(4)));

#define MFMA16(a, b, c) __builtin_amdgcn_mfma_f32_16x16x32_bf16((a), (b), (c), 0, 0, 0)

// async global->LDS, 16B per lane; LDS dest wave-uniform, HW scatters +lane*16
__device__ __forceinline__ void gl2lds16(const bf16_t* g, bf16_t* l) {
    __builtin_amdgcn_global_load_lds(
        (const __attribute__((address_space(1))) unsigned int*)g,
        (__attribute__((address_space(3))) unsigned int*)l, 16, 0, 0);
}

// ---------------------------------------------------------------------------
// fp32 -> bf16 conversion (x)
// ---------------------------------------------------------------------------
__global__ __launch_bounds__(256) void cvt_kernel(
    const float* __restrict__ in, bf16_t* __restrict__ out, int n)
{
    int i = (blockIdx.x * 256 + threadIdx.x) * 4;
    if (i + 3 < n) {
        const float4 v = *(const float4*)(in + i);
        bf16x4 o;
        o[0] = (bf16_t)v.x; o[1] = (bf16_t)v.y;
        o[2] = (bf16_t)v.z; o[3] = (bf16_t)v.w;
        *(bf16x4*)(out + i) = o;
    }
}

// ---------------------------------------------------------------------------
// Merged weight transpose + cast for all 4 weights (blockIdx.y selects).
// Wt layout: [Wq^T | Wk^T | Wv^T | Wo^T], each [1024][1024] bf16.
// ---------------------------------------------------------------------------
__global__ __launch_bounds__(256) void wtr4_kernel(
    const float* __restrict__ W0, const float* __restrict__ W1,
    const float* __restrict__ W2, const float* __restrict__ W3,
    bf16_t* __restrict__ Wt)
{
    __shared__ float T[32][33];
    const int y = blockIdx.y;
    const float* W = (y == 0) ? W0 : (y == 1) ? W1 : (y == 2) ? W2 : W3;
    bf16_t* out = Wt + (size_t)y * DM * DM;
    const int tk0 = (blockIdx.x >> 5) << 5;
    const int tn0 = (blockIdx.x & 31) << 5;
    const int r = threadIdx.x >> 5, c = threadIdx.x & 31;
#pragma unroll
    for (int i = 0; i < 4; ++i)
        T[r + i * 8][c] = W[(size_t)(tk0 + r + i * 8) * DM + tn0 + c];
    __syncthreads();
#pragma unroll
    for (int i = 0; i < 4; ++i)
        out[(size_t)(tn0 + r + i * 8) * DM + tk0 + c] = (bf16_t)T[c][r + i * 8];
}

// ---------------------------------------------------------------------------
// RoPE table: tab[s*32+i] = (cos, sin) of s * 10000^(-i/32)
// ---------------------------------------------------------------------------
__global__ void rope_table_kernel(float2* __restrict__ tab) {
    int idx = blockIdx.x * 256 + threadIdx.x;
    if (idx >= SEQ * 32) return;
    int s = idx >> 5, i = idx & 31;
    float freq = powf(10000.0f, -(float)i / 32.0f);
    float a = (float)s * freq;
    tab[idx] = make_float2(cosf(a), sinf(a));
}

// ---------------------------------------------------------------------------
// Double-buffered 128x128xK(BK=64) MFMA K-loop, global_load_lds staging.
// Per 16KB stage: 16 groups of 512 elems; group g = mt*2+kc holds rows
// mt*16..+15, k-half kc; lane i <-> (row i&15, k (i>>4)*8). Wave w fills
// groups w*4..w*4+3 (covers rows 32w..32w+31, both k-halves).
// One barrier per iter; 32 MFMA per wave per barrier to cover load latency.
// TR (compile-time) swaps MFMA operands -> C^T (V epilogue).
// ---------------------------------------------------------------------------
template<bool TR>
__device__ __forceinline__ void kloop_bk64(
    const bf16_t* __restrict__ Xp, const bf16_t* __restrict__ Wp,
    bf16_t* As, bf16_t* Bs, int tid, f32x4 (&acc)[4][4])
{
    const int lane = tid & 63;
    const int wave = tid >> 6;
    const int wm = wave & 1, wn = wave >> 1;
    const int l = lane & 15, quad = lane >> 4;
    const int rl = lane & 15;
    const int kf = (lane >> 4) << 3;

    const bf16_t* xg[4];
    const bf16_t* wg[4];
    int gidx[4];
#pragma unroll
    for (int j = 0; j < 4; ++j) {
        const int g  = wave * 4 + j;
        const int mt = g >> 1, kc = g & 1;
        gidx[j] = g;
        xg[j] = Xp + (size_t)(mt * 16 + rl) * DM + kc * 32 + kf;
        wg[j] = Wp + (size_t)(mt * 16 + rl) * DM + kc * 32 + kf;
    }

    // prologue: stage k-chunk 0 into buffer 0
#pragma unroll
    for (int j = 0; j < 4; ++j) {
        gl2lds16(xg[j], As + gidx[j] * 512);
        gl2lds16(wg[j], Bs + gidx[j] * 512);
    }

    const int kiters = DM / 64;   // 16
    for (int k = 0; k < kiters; ++k) {
        const int cur = k & 1;
        __syncthreads();                    // drains vmcnt: buf[cur] ready
        if (k + 1 < kiters) {               // prefetch next 64-chunk
            const int nxt = cur ^ 1;
            const int ko = (k + 1) * 64;
#pragma unroll
            for (int j = 0; j < 4; ++j) {
                gl2lds16(xg[j] + ko, As + nxt * 8192 + gidx[j] * 512);
                gl2lds16(wg[j] + ko, Bs + nxt * 8192 + gidx[j] * 512);
            }
        }
        const bf16_t* ab = As + cur * 8192;
        const bf16_t* bb = Bs + cur * 8192;
#pragma unroll
        for (int kc = 0; kc < 2; ++kc) {
            bf16x8 af[4], bw[4];
#pragma unroll
            for (int a = 0; a < 4; ++a) {
                af[a] = *(const bf16x8*)(ab + ((wm * 4 + a) * 2 + kc) * 512 + (quad * 16 + l) * 8);
                bw[a] = *(const bf16x8*)(bb + ((wn * 4 + a) * 2 + kc) * 512 + (quad * 16 + l) * 8);
            }
#pragma unroll
            for (int a = 0; a < 4; ++a)
#pragma unroll
                for (int b = 0; b < 4; ++b)
                    acc[a][b] = TR ? MFMA16(bw[b], af[a], acc[a][b])
                                   : MFMA16(af[a], bw[b], acc[a][b]);
        }
    }
}

// ---------------------------------------------------------------------------
// Merged QKV GEMM: C = X(8192x1024) @ Wqkv^T, Wqkv stored [3072][1024].
// Epilogue by n0: n<1024 Q (RoPE*1/8), n<2048 K (RoPE), else V (C^T direct).
// ---------------------------------------------------------------------------
__global__ __launch_bounds__(256) void gemm_qkv_kernel(
    const bf16_t* __restrict__ X, const bf16_t* __restrict__ Wt,
    bf16_t* __restrict__ Qt, bf16_t* __restrict__ Kt, bf16_t* __restrict__ Vtr,
    const float2* __restrict__ rope)
{
    __shared__ __align__(16) bf16_t As[2 * 128 * 64];
    __shared__ __align__(16) bf16_t Bs[2 * 128 * 64];

    const int tid  = threadIdx.x;
    const int lane = tid & 63;
    const int wave = tid >> 6;
    const int wm   = wave & 1, wn = wave >> 1;
    const int l    = lane & 15;
    const int quad = lane >> 4;

    const int m0 = (blockIdx.x / 24) << 7;
    const int n0 = (blockIdx.x % 24) << 7;
    const bool tr = (n0 >= 2 * DM);   // V range

    f32x4 acc[4][4] = {};
    if (tr) kloop_bk64<true >(X + (size_t)m0 * DM, Wt + (size_t)n0 * DM, As, Bs, tid, acc);
    else    kloop_bk64<false>(X + (size_t)m0 * DM, Wt + (size_t)n0 * DM, As, Bs, tid, acc);

#pragma unroll
    for (int a = 0; a < 4; ++a)
#pragma unroll
        for (int b = 0; b < 4; ++b)
#pragma unroll
            for (int r = 0; r < 4; ++r) {
                float v = acc[a][b][r];
                if (tr) {
                    const int n = n0 + wn * 64 + b * 16 + quad * 4 + r;
                    const int m = m0 + wm * 64 + a * 16 + l;
                    const int bi = m >> 11, s = m & (SEQ - 1);
                    const int col = n & (DM - 1);
                    const int h = col >> 6, d = col & (DK - 1);
                    Vtr[(((size_t)(bi * NH + h)) * DK + d) * SEQ + s] = (bf16_t)v;
                } else {
                    const int m  = m0 + wm * 64 + a * 16 + quad * 4 + r;
                    const int nn = n0 + wn * 64 + b * 16 + l;
                    const int bi = m >> 11, s = m & (SEQ - 1);
                    const int col = nn & (DM - 1);
                    const int h = col >> 6, d = col & (DK - 1);
                    float pv = __shfl_xor(v, 1);
                    float2 cs = rope[s * 32 + (d >> 1)];
                    float res = (d & 1) ? (v * cs.x + pv * cs.y)
                                        : (v * cs.x - pv * cs.y);
                    bf16_t* dst = (nn < DM) ? Qt : Kt;
                    if (nn < DM) res *= 0.125f;   // fold 1/sqrt(dk) into Q
                    dst[(((size_t)(bi * NH + h)) * SEQ + s) * DK + d] = (bf16_t)res;
                }
            }
}

// ---------------------------------------------------------------------------
// Output projection GEMM: d_out(fp32) = Ot(8192x1024,bf16) @ Wot^T.
// ---------------------------------------------------------------------------
__global__ __launch_bounds__(256) void gemm_out_kernel(
    const bf16_t* __restrict__ X, const bf16_t* __restrict__ Wt,
    float* __restrict__ out)
{
    __shared__ __align__(16) bf16_t As[2 * 128 * 64];
    __shared__ __align__(16) bf16_t Bs[2 * 128 * 64];

    const int tid  = threadIdx.x;
    const int lane = tid & 63;
    const int wave = tid >> 6;
    const int wm   = wave & 1, wn = wave >> 1;
    const int l    = lane & 15;
    const int quad = lane >> 4;

    const int m0 = (blockIdx.x >> 3) << 7;
    const int n0 = (blockIdx.x & 7) << 7;

    f32x4 acc[4][4] = {};
    kloop_bk64<false>(X + (size_t)m0 * DM, Wt + (size_t)n0 * DM, As, Bs, tid, acc);

#pragma unroll
    for (int a = 0; a < 4; ++a)
#pragma unroll
        for (int b = 0; b < 4; ++b)
#pragma unroll
            for (int r = 0; r < 4; ++r) {
                const int m  = m0 + wm * 64 + a * 16 + quad * 4 + r;
                const int nn = n0 + wn * 64 + b * 16 + l;
                out[(size_t)m * DM + nn] = acc[a][b][r];
            }
}

// ---------------------------------------------------------------------------
// Causal flash attention (unchanged from round 4/5/6).
// ---------------------------------------------------------------------------
#define KLD 72   // LDS row stride (elems): 144 B

__global__ __launch_bounds__(256) void attn_kernel(
    const bf16_t* __restrict__ Q, const bf16_t* __restrict__ K,
    const bf16_t* __restrict__ Vt, bf16_t* __restrict__ O)
{
    __shared__ __align__(16) bf16_t Kl[64 * KLD];
    __shared__ __align__(16) bf16_t Vl[64 * KLD];
    __shared__ __align__(16) bf16_t Pl[4][32 * KLD];

    const int bh   = blockIdx.y;
    const int tid  = threadIdx.x;
    const int wave = tid >> 6;
    const int lane = tid & 63;
    const int l    = lane & 15;
    const int quad = lane >> 4;
    const int srow = tid >> 3;
    const int sch  = (tid & 7) << 3;

    bf16_t* Pw = Pl[wave];
    const bf16_t* Qb = Q  + (size_t)bh * SEQ * DK;
    const bf16_t* Kb = K  + (size_t)bh * SEQ * DK;
    const bf16_t* Vb = Vt + (size_t)bh * DK * SEQ;
    const int b = bh >> 4, h = bh & 15;

    for (int ph = 0; ph < 2; ++ph) {
        const int qblk = ph ? (15 - (int)blockIdx.x) : (int)blockIdx.x;
        const int q0w  = qblk * 128 + wave * 32;
        const int nch  = 2 * (qblk + 1);

        bf16x8 qb[2][2];
#pragma unroll
        for (int u = 0; u < 2; ++u) {
            qb[u][0] = *(const bf16x8*)(Qb + (size_t)(q0w + u * 16 + l) * DK + quad * 8);
            qb[u][1] = *(const bf16x8*)(Qb + (size_t)(q0w + u * 16 + l) * DK + 32 + quad * 8);
        }

        float m_run[2] = {-3e38f, -3e38f};
        float l_run[2] = {0.f, 0.f};
        f32x4 o[4][2] = {};

        bf16x8 pk0 = *(const bf16x8*)(Kb + (size_t)srow * DK + sch);
        bf16x8 pk1 = *(const bf16x8*)(Kb + (size_t)(32 + srow) * DK + sch);
        bf16x8 pv0 = *(const bf16x8*)(Vb + (size_t)srow * SEQ + sch);
        bf16x8 pv1 = *(const bf16x8*)(Vb + (size_t)(32 + srow) * SEQ + sch);

        for (int i = 0; i < nch; ++i) {
            const int c = i * 64;
            __syncthreads();
            *(bf16x8*)(Kl + srow * KLD + sch)        = pk0;
            *(bf16x8*)(Kl + (32 + srow) * KLD + sch) = pk1;
            *(bf16x8*)(Vl + srow * KLD + sch)        = pv0;
            *(bf16x8*)(Vl + (32 + srow) * KLD + sch) = pv1;
            __syncthreads();
            if (i + 1 < nch) {
                const int cn = c + 64;
                pk0 = *(const bf16x8*)(Kb + (size_t)(cn + srow) * DK + sch);
                pk1 = *(const bf16x8*)(Kb + (size_t)(cn + 32 + srow) * DK + sch);
                pv0 = *(const bf16x8*)(Vb + (size_t)srow * SEQ + cn + sch);
                pv1 = *(const bf16x8*)(Vb + (size_t)(32 + srow) * SEQ + cn + sch);
            }
            if (c > q0w + 31) continue;

            f32x4 st[4][2] = {};
#pragma unroll
            for (int t = 0; t < 4; ++t) {
                const bf16x8 k0 = *(const bf16x8*)(Kl + (t * 16 + l) * KLD + quad * 8);
                const bf16x8 k1 = *(const bf16x8*)(Kl + (t * 16 + l) * KLD + 32 + quad * 8);
                st[t][0] = MFMA16(k0, qb[0][0], st[t][0]);
                st[t][0] = MFMA16(k1, qb[0][1], st[t][0]);
                st[t][1] = MFMA16(k0, qb[1][0], st[t][1]);
                st[t][1] = MFMA16(k1, qb[1][1], st[t][1]);
            }
            if (c + 63 > q0w) {
#pragma unroll
                for (int u = 0; u < 2; ++u) {
                    const int thr = q0w + u * 16 + l - c - quad * 4;
#pragma unroll
                    for (int t = 0; t < 4; ++t)
#pragma unroll
                        for (int r = 0; r < 4; ++r)
                            if (t * 16 + r > thr) st[t][u][r] = -3e38f;
                }
            }
#pragma unroll
            for (int u = 0; u < 2; ++u) {
                float cmax = -3e38f;
#pragma unroll
                for (int t = 0; t < 4; ++t)
#pragma unroll
                    for (int r = 0; r < 4; ++r)
                        cmax = fmaxf(cmax, st[t][u][r]);
                cmax = fmaxf(cmax, __shfl_xor(cmax, 16));
                cmax = fmaxf(cmax, __shfl_xor(cmax, 32));
                const float mnew  = fmaxf(m_run[u], cmax);
                const float alpha = __expf(m_run[u] - mnew);
                m_run[u] = mnew;
                float csum = 0.f;
#pragma unroll
                for (int t = 0; t < 4; ++t)
#pragma unroll
                    for (int r = 0; r < 4; ++r) {
                        st[t][u][r] = __expf(st[t][u][r] - mnew);
                        csum += st[t][u][r];
                    }
                csum += __shfl_xor(csum, 16);
                csum += __shfl_xor(csum, 32);
                l_run[u] = l_run[u] * alpha + csum;
#pragma unroll
                for (int n = 0; n < 4; ++n)
#pragma unroll
                    for (int r = 0; r < 4; ++r)
                        o[n][u][r] *= alpha;
#pragma unroll
                for (int t = 0; t < 4; ++t) {
                    bf16x4 pk;
                    pk[0] = (bf16_t)st[t][u][0]; pk[1] = (bf16_t)st[t][u][1];
                    pk[2] = (bf16_t)st[t][u][2]; pk[3] = (bf16_t)st[t][u][3];
                    *(bf16x4*)(Pw + (u * 16 + l) * KLD + t * 16 + quad * 4) = pk;
                }
            }
            const bf16x8 pb00 = *(const bf16x8*)(Pw + l * KLD + quad * 8);
            const bf16x8 pb01 = *(const bf16x8*)(Pw + l * KLD + 32 + quad * 8);
            const bf16x8 pb10 = *(const bf16x8*)(Pw + (16 + l) * KLD + quad * 8);
            const bf16x8 pb11 = *(const bf16x8*)(Pw + (16 + l) * KLD + 32 + quad * 8);
#pragma unroll
            for (int n = 0; n < 4; ++n) {
                const bf16x8 v0 = *(const bf16x8*)(Vl + (n * 16 + l) * KLD + quad * 8);
                const bf16x8 v1 = *(const bf16x8*)(Vl + (n * 16 + l) * KLD + 32 + quad * 8);
                o[n][0] = MFMA16(v0, pb00, o[n][0]);
                o[n][0] = MFMA16(v1, pb01, o[n][0]);
                o[n][1] = MFMA16(v0, pb10, o[n][1]);
                o[n][1] = MFMA16(v1, pb11, o[n][1]);
            }
        }

#pragma unroll
        for (int u = 0; u < 2; ++u) {
            const float inv = 1.0f / l_run[u];
#pragma unroll
            for (int n = 0; n < 4; ++n) {
                bf16x4 ov;
                ov[0] = (bf16_t)(o[n][u][0] * inv); ov[1] = (bf16_t)(o[n][u][1] * inv);
                ov[2] = (bf16_t)(o[n][u][2] * inv); ov[3] = (bf16_t)(o[n][u][3] * inv);
                *(bf16x4*)(Pw + (u * 16 + l) * KLD + n * 16 + quad * 4) = ov;
            }
        }
        const int row  = lane >> 1;
        const int half = (lane & 1) * 32;
        const bf16x8 w0 = *(const bf16x8*)(Pw + row * KLD + half);
        const bf16x8 w1 = *(const bf16x8*)(Pw + row * KLD + half + 8);
        const bf16x8 w2 = *(const bf16x8*)(Pw + row * KLD + half + 16);
        const bf16x8 w3 = *(const bf16x8*)(Pw + row * KLD + half + 24);
        bf16_t* op = O + ((size_t)(b * SEQ + qblk * 128 + wave * 32 + row)) * DM
                       + h * DK + half;
        *(bf16x8*)(op)      = w0;
        *(bf16x8*)(op + 8)  = w1;
        *(bf16x8*)(op + 16) = w2;
        *(bf16x8*)(op + 24) = w3;
    }
}

// ---------------------------------------------------------------------------
extern "C" void kernel_launch(void* const* d_in, const int* in_sizes, int n_in,
                              void* d_out, int out_size, void* d_ws, size_t ws_size,
                              hipStream_t stream)
{
    const float* x  = (const float*)d_in[0];
    const float* Wq = (const float*)d_in[1];
    const float* Wk = (const float*)d_in[2];
    const float* Wv = (const float*)d_in[3];
    const float* Wo = (const float*)d_in[4];

    char* ws = (char*)d_ws;
    float2* rope = (float2*)ws;                        // 512 KiB
    const size_t TEN = (size_t)MROWS * DM;
    const size_t WEL = (size_t)DM * DM;
    bf16_t* xb    = (bf16_t*)(ws + (1 << 19));
    bf16_t* Wqkvt = xb + TEN;                          // [3072][1024] concat
    bf16_t* Wot   = Wqkvt + 3 * WEL;                   // contiguous 4th weight
    bf16_t* Qt    = Wot + WEL;
    bf16_t* Kt    = Qt + TEN;
    bf16_t* Vt    = Kt + TEN;
    bf16_t* Ot    = Vt + TEN;

    rope_table_kernel<<<(SEQ * 32 + 255) / 256, 256, 0, stream>>>(rope);

    cvt_kernel<<<(int)(TEN / 4 / 256), 256, 0, stream>>>(x, xb, (int)TEN);
    wtr4_kernel<<<dim3(1024, 4), 256, 0, stream>>>(Wq, Wk, Wv, Wo, Wqkvt);

    // merged QKV: 64 m-tiles x 24 n-tiles
    gemm_qkv_kernel<<<64 * 24, 256, 0, stream>>>(xb, Wqkvt, Qt, Kt, Vt, rope);

    attn_kernel<<<dim3(8, NB * NH), 256, 0, stream>>>(Qt, Kt, Vt, Ot);

    gemm_out_kernel<<<64 * 8, 256, 0, stream>>>(Ot, Wot, (float*)d_out);
}

// Round 8
// 362.860 us; speedup vs baseline: 1.0437x; 1.0437x over previous
//
#include <hip/hip_runtime.h>
#include <hip/hip_bf16.h>

// Problem constants: B=4, S=2048, D=1024, H=16, dk=64
#define SEQ   2048
#define NB    4
#define NH    16
#define DK    64
#define DM    1024
#define MROWS (NB * SEQ)   // 8192

typedef __bf16 bf16_t;
typedef __bf16 bf16x8 __attribute__((ext_vector_type(8)));
typedef __bf16 bf16x4 __attribute__((ext_vector_type(4)));
typedef float  f32x4  __attribute__((ext_vector_type(4)));

#define MFMA16(a, b, c) __builtin_amdgcn_mfma_f32_16x16x32_bf16((a), (b), (c), 0, 0, 0)

// async global->LDS, 16B per lane; LDS dest wave-uniform, HW scatters +lane*16
__device__ __forceinline__ void gl2lds16(const bf16_t* g, bf16_t* l) {
    __builtin_amdgcn_global_load_lds(
        (const __attribute__((address_space(1))) unsigned int*)g,
        (__attribute__((address_space(3))) unsigned int*)l, 16, 0, 0);
}

// ---------------------------------------------------------------------------
// fp32 -> bf16 conversion (x)
// ---------------------------------------------------------------------------
__global__ __launch_bounds__(256) void cvt_kernel(
    const float* __restrict__ in, bf16_t* __restrict__ out, int n)
{
    int i = (blockIdx.x * 256 + threadIdx.x) * 4;
    if (i + 3 < n) {
        const float4 v = *(const float4*)(in + i);
        bf16x4 o;
        o[0] = (bf16_t)v.x; o[1] = (bf16_t)v.y;
        o[2] = (bf16_t)v.z; o[3] = (bf16_t)v.w;
        *(bf16x4*)(out + i) = o;
    }
}

// ---------------------------------------------------------------------------
// Merged weight transpose + cast for all 4 weights (blockIdx.y selects).
// Wt layout: [Wq^T | Wk^T | Wv^T | Wo^T], each [1024][1024] bf16.
// ---------------------------------------------------------------------------
__global__ __launch_bounds__(256) void wtr4_kernel(
    const float* __restrict__ W0, const float* __restrict__ W1,
    const float* __restrict__ W2, const float* __restrict__ W3,
    bf16_t* __restrict__ Wt)
{
    __shared__ float T[32][33];
    const int y = blockIdx.y;
    const float* W = (y == 0) ? W0 : (y == 1) ? W1 : (y == 2) ? W2 : W3;
    bf16_t* out = Wt + (size_t)y * DM * DM;
    const int tk0 = (blockIdx.x >> 5) << 5;
    const int tn0 = (blockIdx.x & 31) << 5;
    const int r = threadIdx.x >> 5, c = threadIdx.x & 31;
#pragma unroll
    for (int i = 0; i < 4; ++i)
        T[r + i * 8][c] = W[(size_t)(tk0 + r + i * 8) * DM + tn0 + c];
    __syncthreads();
#pragma unroll
    for (int i = 0; i < 4; ++i)
        out[(size_t)(tn0 + r + i * 8) * DM + tk0 + c] = (bf16_t)T[c][r + i * 8];
}

// ---------------------------------------------------------------------------
// RoPE table: tab[s*32+i] = (cos, sin) of s * 10000^(-i/32)
// ---------------------------------------------------------------------------
__global__ void rope_table_kernel(float2* __restrict__ tab) {
    int idx = blockIdx.x * 256 + threadIdx.x;
    if (idx >= SEQ * 32) return;
    int s = idx >> 5, i = idx & 31;
    float freq = powf(10000.0f, -(float)i / 32.0f);
    float a = (float)s * freq;
    tab[idx] = make_float2(cosf(a), sinf(a));
}

// ---------------------------------------------------------------------------
// Double-buffered 128x64xK(BK=32) MFMA K-loop, global_load_lds staging.
// Small tile (acc 4x2 = 32 AGPR, 24 KB LDS) -> ~5 resident blocks/CU for
// latency hiding via cross-block overlap (round-7 lesson: occupancy beats
// per-barrier MFMA count).
// A: 8 groups of 512 elems (16 rows x 32k, lane i <-> row i&15, k (i>>4)*8),
// B: 4 groups. Wave w stages A groups 2w,2w+1 and B group w.
// TR (compile-time) swaps MFMA operands -> C^T (V epilogue).
// ---------------------------------------------------------------------------
template<bool TR>
__device__ __forceinline__ void kloop_128x64(
    const bf16_t* __restrict__ Xp, const bf16_t* __restrict__ Wp,
    bf16_t* As, bf16_t* Bs, int tid, f32x4 (&acc)[4][2])
{
    const int lane = tid & 63;
    const int wave = tid >> 6;
    const int wm = wave & 1, wn = wave >> 1;
    const int l = lane & 15, quad = lane >> 4;
    const int rl = lane & 15;
    const int kf = (lane >> 4) << 3;

    const bf16_t* xa0 = Xp + (size_t)((wave * 2)     * 16 + rl) * DM + kf;
    const bf16_t* xa1 = Xp + (size_t)((wave * 2 + 1) * 16 + rl) * DM + kf;
    const bf16_t* wb0 = Wp + (size_t)(wave * 16 + rl) * DM + kf;

    // prologue: stage k-chunk 0 into buffer 0
    gl2lds16(xa0, As + (wave * 2) * 512);
    gl2lds16(xa1, As + (wave * 2 + 1) * 512);
    gl2lds16(wb0, Bs + wave * 512);

    const int kiters = DM / 32;   // 32
    for (int k = 0; k < kiters; ++k) {
        const int cur = k & 1;
        __syncthreads();                    // drains vmcnt: buf[cur] ready
        if (k + 1 < kiters) {               // prefetch next chunk
            const int nxt = cur ^ 1;
            const int ko = (k + 1) * 32;
            gl2lds16(xa0 + ko, As + nxt * 4096 + (wave * 2) * 512);
            gl2lds16(xa1 + ko, As + nxt * 4096 + (wave * 2 + 1) * 512);
            gl2lds16(wb0 + ko, Bs + nxt * 2048 + wave * 512);
        }
        const bf16_t* ab = As + cur * 4096;
        const bf16_t* bb = Bs + cur * 2048;
        bf16x8 af[4], bw[2];
#pragma unroll
        for (int a = 0; a < 4; ++a)
            af[a] = *(const bf16x8*)(ab + (wm * 4 + a) * 512 + (quad * 16 + l) * 8);
#pragma unroll
        for (int b = 0; b < 2; ++b)
            bw[b] = *(const bf16x8*)(bb + (wn * 2 + b) * 512 + (quad * 16 + l) * 8);
#pragma unroll
        for (int a = 0; a < 4; ++a)
#pragma unroll
            for (int b = 0; b < 2; ++b)
                acc[a][b] = TR ? MFMA16(bw[b], af[a], acc[a][b])
                               : MFMA16(af[a], bw[b], acc[a][b]);
    }
}

// ---------------------------------------------------------------------------
// Merged QKV GEMM: C = X(8192x1024) @ Wqkv^T, Wqkv stored [3072][1024].
// n-outer grid: bx>>6 = n-tile (48 of 64), bx&63 = m-tile (64 of 128).
// Epilogue by n0: n<1024 Q (RoPE*1/8), n<2048 K (RoPE), else V (C^T direct).
// ---------------------------------------------------------------------------
__global__ __launch_bounds__(256, 4) void gemm_qkv_kernel(
    const bf16_t* __restrict__ X, const bf16_t* __restrict__ Wt,
    bf16_t* __restrict__ Qt, bf16_t* __restrict__ Kt, bf16_t* __restrict__ Vtr,
    const float2* __restrict__ rope)
{
    __shared__ __align__(16) bf16_t As[2 * 128 * 32];
    __shared__ __align__(16) bf16_t Bs[2 * 64 * 32];

    const int tid  = threadIdx.x;
    const int lane = tid & 63;
    const int wave = tid >> 6;
    const int wm   = wave & 1, wn = wave >> 1;
    const int l    = lane & 15;
    const int quad = lane >> 4;

    const int n0 = (blockIdx.x >> 6) << 6;   // 48 n-tiles of 64
    const int m0 = (blockIdx.x & 63) << 7;   // 64 m-tiles of 128
    const bool tr = (n0 >= 2 * DM);          // V range

    f32x4 acc[4][2] = {};
    if (tr) kloop_128x64<true >(X + (size_t)m0 * DM, Wt + (size_t)n0 * DM, As, Bs, tid, acc);
    else    kloop_128x64<false>(X + (size_t)m0 * DM, Wt + (size_t)n0 * DM, As, Bs, tid, acc);

#pragma unroll
    for (int a = 0; a < 4; ++a)
#pragma unroll
        for (int b = 0; b < 2; ++b)
#pragma unroll
            for (int r = 0; r < 4; ++r) {
                float v = acc[a][b][r];
                if (tr) {
                    const int n = n0 + wn * 32 + b * 16 + quad * 4 + r;
                    const int m = m0 + wm * 64 + a * 16 + l;
                    const int bi = m >> 11, s = m & (SEQ - 1);
                    const int col = n & (DM - 1);
                    const int h = col >> 6, d = col & (DK - 1);
                    Vtr[(((size_t)(bi * NH + h)) * DK + d) * SEQ + s] = (bf16_t)v;
                } else {
                    const int m  = m0 + wm * 64 + a * 16 + quad * 4 + r;
                    const int nn = n0 + wn * 32 + b * 16 + l;
                    const int bi = m >> 11, s = m & (SEQ - 1);
                    const int col = nn & (DM - 1);
                    const int h = col >> 6, d = col & (DK - 1);
                    float pv = __shfl_xor(v, 1);
                    float2 cs = rope[s * 32 + (d >> 1)];
                    float res = (d & 1) ? (v * cs.x + pv * cs.y)
                                        : (v * cs.x - pv * cs.y);
                    bf16_t* dst = (nn < DM) ? Qt : Kt;
                    if (nn < DM) res *= 0.125f;   // fold 1/sqrt(dk) into Q
                    dst[(((size_t)(bi * NH + h)) * SEQ + s) * DK + d] = (bf16_t)res;
                }
            }
}

// ---------------------------------------------------------------------------
// Output projection GEMM: d_out(fp32) = Ot(8192x1024,bf16) @ Wot^T.
// ---------------------------------------------------------------------------
__global__ __launch_bounds__(256, 4) void gemm_out_kernel(
    const bf16_t* __restrict__ X, const bf16_t* __restrict__ Wt,
    float* __restrict__ out)
{
    __shared__ __align__(16) bf16_t As[2 * 128 * 32];
    __shared__ __align__(16) bf16_t Bs[2 * 64 * 32];

    const int tid  = threadIdx.x;
    const int lane = tid & 63;
    const int wave = tid >> 6;
    const int wm   = wave & 1, wn = wave >> 1;
    const int l    = lane & 15;
    const int quad = lane >> 4;

    const int n0 = (blockIdx.x >> 6) << 6;   // 16 n-tiles
    const int m0 = (blockIdx.x & 63) << 7;   // 64 m-tiles

    f32x4 acc[4][2] = {};
    kloop_128x64<false>(X + (size_t)m0 * DM, Wt + (size_t)n0 * DM, As, Bs, tid, acc);

#pragma unroll
    for (int a = 0; a < 4; ++a)
#pragma unroll
        for (int b = 0; b < 2; ++b)
#pragma unroll
            for (int r = 0; r < 4; ++r) {
                const int m  = m0 + wm * 64 + a * 16 + quad * 4 + r;
                const int nn = n0 + wn * 32 + b * 16 + l;
                out[(size_t)m * DM + nn] = acc[a][b][r];
            }
}

// ---------------------------------------------------------------------------
// Causal flash attention (unchanged from round 4/5/6).
// ---------------------------------------------------------------------------
#define KLD 72   // LDS row stride (elems): 144 B

__global__ __launch_bounds__(256) void attn_kernel(
    const bf16_t* __restrict__ Q, const bf16_t* __restrict__ K,
    const bf16_t* __restrict__ Vt, bf16_t* __restrict__ O)
{
    __shared__ __align__(16) bf16_t Kl[64 * KLD];
    __shared__ __align__(16) bf16_t Vl[64 * KLD];
    __shared__ __align__(16) bf16_t Pl[4][32 * KLD];

    const int bh   = blockIdx.y;
    const int tid  = threadIdx.x;
    const int wave = tid >> 6;
    const int lane = tid & 63;
    const int l    = lane & 15;
    const int quad = lane >> 4;
    const int srow = tid >> 3;
    const int sch  = (tid & 7) << 3;

    bf16_t* Pw = Pl[wave];
    const bf16_t* Qb = Q  + (size_t)bh * SEQ * DK;
    const bf16_t* Kb = K  + (size_t)bh * SEQ * DK;
    const bf16_t* Vb = Vt + (size_t)bh * DK * SEQ;
    const int b = bh >> 4, h = bh & 15;

    for (int ph = 0; ph < 2; ++ph) {
        const int qblk = ph ? (15 - (int)blockIdx.x) : (int)blockIdx.x;
        const int q0w  = qblk * 128 + wave * 32;
        const int nch  = 2 * (qblk + 1);

        bf16x8 qb[2][2];
#pragma unroll
        for (int u = 0; u < 2; ++u) {
            qb[u][0] = *(const bf16x8*)(Qb + (size_t)(q0w + u * 16 + l) * DK + quad * 8);
            qb[u][1] = *(const bf16x8*)(Qb + (size_t)(q0w + u * 16 + l) * DK + 32 + quad * 8);
        }

        float m_run[2] = {-3e38f, -3e38f};
        float l_run[2] = {0.f, 0.f};
        f32x4 o[4][2] = {};

        bf16x8 pk0 = *(const bf16x8*)(Kb + (size_t)srow * DK + sch);
        bf16x8 pk1 = *(const bf16x8*)(Kb + (size_t)(32 + srow) * DK + sch);
        bf16x8 pv0 = *(const bf16x8*)(Vb + (size_t)srow * SEQ + sch);
        bf16x8 pv1 = *(const bf16x8*)(Vb + (size_t)(32 + srow) * SEQ + sch);

        for (int i = 0; i < nch; ++i) {
            const int c = i * 64;
            __syncthreads();
            *(bf16x8*)(Kl + srow * KLD + sch)        = pk0;
            *(bf16x8*)(Kl + (32 + srow) * KLD + sch) = pk1;
            *(bf16x8*)(Vl + srow * KLD + sch)        = pv0;
            *(bf16x8*)(Vl + (32 + srow) * KLD + sch) = pv1;
            __syncthreads();
            if (i + 1 < nch) {
                const int cn = c + 64;
                pk0 = *(const bf16x8*)(Kb + (size_t)(cn + srow) * DK + sch);
                pk1 = *(const bf16x8*)(Kb + (size_t)(cn + 32 + srow) * DK + sch);
                pv0 = *(const bf16x8*)(Vb + (size_t)srow * SEQ + cn + sch);
                pv1 = *(const bf16x8*)(Vb + (size_t)(32 + srow) * SEQ + cn + sch);
            }
            if (c > q0w + 31) continue;

            f32x4 st[4][2] = {};
#pragma unroll
            for (int t = 0; t < 4; ++t) {
                const bf16x8 k0 = *(const bf16x8*)(Kl + (t * 16 + l) * KLD + quad * 8);
                const bf16x8 k1 = *(const bf16x8*)(Kl + (t * 16 + l) * KLD + 32 + quad * 8);
                st[t][0] = MFMA16(k0, qb[0][0], st[t][0]);
                st[t][0] = MFMA16(k1, qb[0][1], st[t][0]);
                st[t][1] = MFMA16(k0, qb[1][0], st[t][1]);
                st[t][1] = MFMA16(k1, qb[1][1], st[t][1]);
            }
            if (c + 63 > q0w) {
#pragma unroll
                for (int u = 0; u < 2; ++u) {
                    const int thr = q0w + u * 16 + l - c - quad * 4;
#pragma unroll
                    for (int t = 0; t < 4; ++t)
#pragma unroll
                        for (int r = 0; r < 4; ++r)
                            if (t * 16 + r > thr) st[t][u][r] = -3e38f;
                }
            }
#pragma unroll
            for (int u = 0; u < 2; ++u) {
                float cmax = -3e38f;
#pragma unroll
                for (int t = 0; t < 4; ++t)
#pragma unroll
                    for (int r = 0; r < 4; ++r)
                        cmax = fmaxf(cmax, st[t][u][r]);
                cmax = fmaxf(cmax, __shfl_xor(cmax, 16));
                cmax = fmaxf(cmax, __shfl_xor(cmax, 32));
                const float mnew  = fmaxf(m_run[u], cmax);
                const float alpha = __expf(m_run[u] - mnew);
                m_run[u] = mnew;
                float csum = 0.f;
#pragma unroll
                for (int t = 0; t < 4; ++t)
#pragma unroll
                    for (int r = 0; r < 4; ++r) {
                        st[t][u][r] = __expf(st[t][u][r] - mnew);
                        csum += st[t][u][r];
                    }
                csum += __shfl_xor(csum, 16);
                csum += __shfl_xor(csum, 32);
                l_run[u] = l_run[u] * alpha + csum;
#pragma unroll
                for (int n = 0; n < 4; ++n)
#pragma unroll
                    for (int r = 0; r < 4; ++r)
                        o[n][u][r] *= alpha;
#pragma unroll
                for (int t = 0; t < 4; ++t) {
                    bf16x4 pk;
                    pk[0] = (bf16_t)st[t][u][0]; pk[1] = (bf16_t)st[t][u][1];
                    pk[2] = (bf16_t)st[t][u][2]; pk[3] = (bf16_t)st[t][u][3];
                    *(bf16x4*)(Pw + (u * 16 + l) * KLD + t * 16 + quad * 4) = pk;
                }
            }
            const bf16x8 pb00 = *(const bf16x8*)(Pw + l * KLD + quad * 8);
            const bf16x8 pb01 = *(const bf16x8*)(Pw + l * KLD + 32 + quad * 8);
            const bf16x8 pb10 = *(const bf16x8*)(Pw + (16 + l) * KLD + quad * 8);
            const bf16x8 pb11 = *(const bf16x8*)(Pw + (16 + l) * KLD + 32 + quad * 8);
#pragma unroll
            for (int n = 0; n < 4; ++n) {
                const bf16x8 v0 = *(const bf16x8*)(Vl + (n * 16 + l) * KLD + quad * 8);
                const bf16x8 v1 = *(const bf16x8*)(Vl + (n * 16 + l) * KLD + 32 + quad * 8);
                o[n][0] = MFMA16(v0, pb00, o[n][0]);
                o[n][0] = MFMA16(v1, pb01, o[n][0]);
                o[n][1] = MFMA16(v0, pb10, o[n][1]);
                o[n][1] = MFMA16(v1, pb11, o[n][1]);
            }
        }

#pragma unroll
        for (int u = 0; u < 2; ++u) {
            const float inv = 1.0f / l_run[u];
#pragma unroll
            for (int n = 0; n < 4; ++n) {
                bf16x4 ov;
                ov[0] = (bf16_t)(o[n][u][0] * inv); ov[1] = (bf16_t)(o[n][u][1] * inv);
                ov[2] = (bf16_t)(o[n][u][2] * inv); ov[3] = (bf16_t)(o[n][u][3] * inv);
                *(bf16x4*)(Pw + (u * 16 + l) * KLD + n * 16 + quad * 4) = ov;
            }
        }
        const int row  = lane >> 1;
        const int half = (lane & 1) * 32;
        const bf16x8 w0 = *(const bf16x8*)(Pw + row * KLD + half);
        const bf16x8 w1 = *(const bf16x8*)(Pw + row * KLD + half + 8);
        const bf16x8 w2 = *(const bf16x8*)(Pw + row * KLD + half + 16);
        const bf16x8 w3 = *(const bf16x8*)(Pw + row * KLD + half + 24);
        bf16_t* op = O + ((size_t)(b * SEQ + qblk * 128 + wave * 32 + row)) * DM
                       + h * DK + half;
        *(bf16x8*)(op)      = w0;
        *(bf16x8*)(op + 8)  = w1;
        *(bf16x8*)(op + 16) = w2;
        *(bf16x8*)(op + 24) = w3;
    }
}

// ---------------------------------------------------------------------------
extern "C" void kernel_launch(void* const* d_in, const int* in_sizes, int n_in,
                              void* d_out, int out_size, void* d_ws, size_t ws_size,
                              hipStream_t stream)
{
    const float* x  = (const float*)d_in[0];
    const float* Wq = (const float*)d_in[1];
    const float* Wk = (const float*)d_in[2];
    const float* Wv = (const float*)d_in[3];
    const float* Wo = (const float*)d_in[4];

    char* ws = (char*)d_ws;
    float2* rope = (float2*)ws;                        // 512 KiB
    const size_t TEN = (size_t)MROWS * DM;
    const size_t WEL = (size_t)DM * DM;
    bf16_t* xb    = (bf16_t*)(ws + (1 << 19));
    bf16_t* Wqkvt = xb + TEN;                          // [3072][1024] concat
    bf16_t* Wot   = Wqkvt + 3 * WEL;                   // contiguous 4th weight
    bf16_t* Qt    = Wot + WEL;
    bf16_t* Kt    = Qt + TEN;
    bf16_t* Vt    = Kt + TEN;
    bf16_t* Ot    = Vt + TEN;

    rope_table_kernel<<<(SEQ * 32 + 255) / 256, 256, 0, stream>>>(rope);

    cvt_kernel<<<(int)(TEN / 4 / 256), 256, 0, stream>>>(x, xb, (int)TEN);
    wtr4_kernel<<<dim3(1024, 4), 256, 0, stream>>>(Wq, Wk, Wv, Wo, Wqkvt);

    // merged QKV: 48 n-tiles (outer) x 64 m-tiles
    gemm_qkv_kernel<<<48 * 64, 256, 0, stream>>>(xb, Wqkvt, Qt, Kt, Vt, rope);

    attn_kernel<<<dim3(8, NB * NH), 256, 0, stream>>>(Qt, Kt, Vt, Ot);

    gemm_out_kernel<<<16 * 64, 256, 0, stream>>>(Ot, Wot, (float*)d_out);
}